// Round 1
// baseline (6077.454 us; speedup 1.0000x reference)
//
#include <hip/hip_runtime.h>

#define ATOM  14
#define BOND  3
#define INNER 20
#define HID   34
#define REC   20
#define OHID  25
#define NN    1048576
#define NE    983040
#define NG    16384
#define MAXD  16

__device__ __forceinline__ float leaky(float x) { return x >= 0.f ? x : 0.01f * x; }

// hc[i] = 0 for all nodes
__global__ void k_init_hc(unsigned char* hc) {
    int i = blockIdx.x * 256 + threadIdx.x;
    if (i < NN) hc[i] = 0;
}

// mark parents, record parent depth per edge
__global__ void k_edge_pre(const int* __restrict__ parent, const int* __restrict__ depth,
                           unsigned char* __restrict__ hc, unsigned char* __restrict__ dp) {
    int e = blockIdx.x * 256 + threadIdx.x;
    if (e >= NE) return;
    int p = parent[e];
    hc[p] = 1;                       // racy same-value stores: fine
    dp[e] = (unsigned char)depth[p];
}

// leaf MLP for childless nodes; zero h rows for internal nodes; build nd[]
__global__ void k_leaf(const float* __restrict__ atom, const int* __restrict__ depth,
                       const unsigned char* __restrict__ hc,
                       const float* __restrict__ w1, const float* __restrict__ b1,
                       const float* __restrict__ w2, const float* __restrict__ b2,
                       float* __restrict__ h, unsigned char* __restrict__ nd) {
    int i = blockIdx.x * 256 + threadIdx.x;
    if (i >= NN) return;
    unsigned char c = hc[i];
    nd[i] = c ? (unsigned char)depth[i] : (unsigned char)255;
    float* hrow = h + (size_t)i * REC;
    if (c) {
        #pragma unroll
        for (int j = 0; j < REC; ++j) hrow[j] = 0.f;   // accumulation target
        return;
    }
    float a[ATOM];
    #pragma unroll
    for (int k = 0; k < ATOM; ++k) a[k] = atom[(size_t)i * ATOM + k];
    float hid[HID];
    #pragma unroll
    for (int j = 0; j < HID; ++j) hid[j] = b1[j];
    for (int k = 0; k < ATOM; ++k) {
        float ak = a[k];
        #pragma unroll
        for (int j = 0; j < HID; ++j) hid[j] += ak * w1[k * HID + j];
    }
    #pragma unroll
    for (int j = 0; j < HID; ++j) hid[j] = leaky(hid[j]);
    float o[REC];
    #pragma unroll
    for (int j = 0; j < REC; ++j) o[j] = b2[j];
    for (int k = 0; k < HID; ++k) {
        float hk = hid[k];
        #pragma unroll
        for (int j = 0; j < REC; ++j) o[j] += hk * w2[k * REC + j];
    }
    #pragma unroll
    for (int j = 0; j < REC; ++j) hrow[j] = leaky(o[j]);
}

// edges whose parent sits at depth d: msg -> atomicAdd into h[parent]
__global__ void k_edge(int d, const unsigned char* __restrict__ dp,
                       const int* __restrict__ parent, const int* __restrict__ child,
                       const float* __restrict__ bond,
                       const float* __restrict__ iw, const float* __restrict__ ib,
                       float* __restrict__ h) {
    int e = blockIdx.x * 256 + threadIdx.x;
    if (e >= NE) return;
    if (dp[e] != (unsigned char)d) return;
    int p = parent[e], c = child[e];
    float x[BOND + REC];
    x[0] = bond[(size_t)e * BOND + 0];
    x[1] = bond[(size_t)e * BOND + 1];
    x[2] = bond[(size_t)e * BOND + 2];
    const float* ch = h + (size_t)c * REC;
    #pragma unroll
    for (int k = 0; k < REC; ++k) x[BOND + k] = ch[k];
    float m[INNER];
    #pragma unroll
    for (int j = 0; j < INNER; ++j) m[j] = ib[j];
    for (int k = 0; k < BOND + REC; ++k) {
        float xk = x[k];
        #pragma unroll
        for (int j = 0; j < INNER; ++j) m[j] += xk * iw[k * INNER + j];
    }
    float* pr = h + (size_t)p * REC;
    #pragma unroll
    for (int j = 0; j < INNER; ++j) atomicAdd(&pr[j], leaky(m[j]));
}

// nodes at depth d with children: MLP([atom, inner_sum]) -> h in place
__global__ void k_node(int d, const unsigned char* __restrict__ nd,
                       const float* __restrict__ atom,
                       const float* __restrict__ w1, const float* __restrict__ b1,
                       const float* __restrict__ w2, const float* __restrict__ b2,
                       float* __restrict__ h) {
    int i = blockIdx.x * 256 + threadIdx.x;
    if (i >= NN) return;
    if (nd[i] != (unsigned char)d) return;
    float x[ATOM + INNER];
    #pragma unroll
    for (int k = 0; k < ATOM; ++k) x[k] = atom[(size_t)i * ATOM + k];
    float* hrow = h + (size_t)i * REC;
    #pragma unroll
    for (int k = 0; k < INNER; ++k) x[ATOM + k] = hrow[k];
    float hid[HID];
    #pragma unroll
    for (int j = 0; j < HID; ++j) hid[j] = b1[j];
    for (int k = 0; k < ATOM + INNER; ++k) {
        float xk = x[k];
        #pragma unroll
        for (int j = 0; j < HID; ++j) hid[j] += xk * w1[k * HID + j];
    }
    #pragma unroll
    for (int j = 0; j < HID; ++j) hid[j] = leaky(hid[j]);
    float o[REC];
    #pragma unroll
    for (int j = 0; j < REC; ++j) o[j] = b2[j];
    for (int k = 0; k < HID; ++k) {
        float hk = hid[k];
        #pragma unroll
        for (int j = 0; j < REC; ++j) o[j] += hk * w2[k * REC + j];
    }
    #pragma unroll
    for (int j = 0; j < REC; ++j) hrow[j] = leaky(o[j]);
}

__global__ void k_zero_g(float* g) {
    int i = blockIdx.x * 256 + threadIdx.x;
    if (i < NG * REC) g[i] = 0.f;
}

__global__ void k_root(const float* __restrict__ isr, const int* __restrict__ gid,
                       const float* __restrict__ h, float* __restrict__ g) {
    int i = blockIdx.x * 256 + threadIdx.x;
    if (i >= NN) return;
    float r = isr[i];
    if (r == 0.f) return;
    int t = gid[i];
    const float* hr = h + (size_t)i * REC;
    float* gr = g + (size_t)t * REC;
    #pragma unroll
    for (int j = 0; j < REC; ++j) atomicAdd(&gr[j], hr[j] * r);
}

__global__ void k_out(const float* __restrict__ g,
                      const float* __restrict__ w1, const float* __restrict__ b1,
                      const float* __restrict__ w2, const float* __restrict__ b2,
                      float* __restrict__ out) {
    int t = blockIdx.x * 256 + threadIdx.x;
    if (t >= NG) return;
    const float* gv = g + (size_t)t * REC;
    float gl[REC];
    #pragma unroll
    for (int k = 0; k < REC; ++k) gl[k] = gv[k];
    float acc = b2[0];
    for (int j = 0; j < OHID; ++j) {
        float s = b1[j];
        #pragma unroll
        for (int k = 0; k < REC; ++k) s += gl[k] * w1[k * OHID + j];
        acc += tanhf(s) * w2[j];
    }
    out[t] = acc;
}

extern "C" void kernel_launch(void* const* d_in, const int* in_sizes, int n_in,
                              void* d_out, int out_size, void* d_ws, size_t ws_size,
                              hipStream_t stream) {
    const float* atom    = (const float*)d_in[0];
    const float* bond    = (const float*)d_in[1];
    const int*   parent  = (const int*)d_in[2];
    const int*   child   = (const int*)d_in[3];
    const int*   depth   = (const int*)d_in[4];
    const int*   gid     = (const int*)d_in[5];
    const float* isr     = (const float*)d_in[6];
    const float* inner_w = (const float*)d_in[7];
    const float* inner_b = (const float*)d_in[8];
    const float* net_w1  = (const float*)d_in[9];
    const float* net_b1  = (const float*)d_in[10];
    const float* net_w2  = (const float*)d_in[11];
    const float* net_b2  = (const float*)d_in[12];
    const float* net0_w1 = (const float*)d_in[13];
    const float* net0_b1 = (const float*)d_in[14];
    const float* net0_w2 = (const float*)d_in[15];
    const float* net0_b2 = (const float*)d_in[16];
    const float* out_w1  = (const float*)d_in[17];
    const float* out_b1  = (const float*)d_in[18];
    const float* out_w2  = (const float*)d_in[19];
    const float* out_b2  = (const float*)d_in[20];
    float* out = (float*)d_out;

    char* ws = (char*)d_ws;
    float* h = (float*)ws;                                         // NN*REC f32
    float* g = (float*)(ws + (size_t)NN * REC * 4);                // NG*REC f32
    unsigned char* dp = (unsigned char*)(ws + (size_t)NN * REC * 4 + (size_t)NG * REC * 4); // NE
    unsigned char* nd = dp + NE;                                   // NN
    unsigned char* hc = nd + NN;                                   // NN

    dim3 B(256);
    int nbN = (NN + 255) / 256;
    int nbE = (NE + 255) / 256;

    k_init_hc<<<nbN, B, 0, stream>>>(hc);
    k_edge_pre<<<nbE, B, 0, stream>>>(parent, depth, hc, dp);
    k_leaf<<<nbN, B, 0, stream>>>(atom, depth, hc, net0_w1, net0_b1, net0_w2, net0_b2, h, nd);
    for (int d = MAXD - 2; d >= 0; --d) {
        k_edge<<<nbE, B, 0, stream>>>(d, dp, parent, child, bond, inner_w, inner_b, h);
        k_node<<<nbN, B, 0, stream>>>(d, nd, atom, net_w1, net_b1, net_w2, net_b2, h);
    }
    k_zero_g<<<(NG * REC + 255) / 256, B, 0, stream>>>(g);
    k_root<<<nbN, B, 0, stream>>>(isr, gid, h, g);
    k_out<<<(NG + 255) / 256, B, 0, stream>>>(g, out_w1, out_b1, out_w2, out_b2, out);
}

// Round 2
// 4158.556 us; speedup vs baseline: 1.4614x; 1.4614x over previous
//
#include <hip/hip_runtime.h>

#define ATOM  14
#define BOND  3
#define INNER 20
#define HID   34
#define REC   20
#define OHID  25
#define NN    1048576
#define NE    983040
#define NG    16384
#define MAXD  16

__device__ __forceinline__ float leaky(float x) { return x >= 0.f ? x : 0.01f * x; }

// ---------- init ----------
__global__ void k_init_hc(unsigned char* hc) {
    int i = blockIdx.x * 256 + threadIdx.x;
    if (i < NN) hc[i] = 0;
}

__global__ void k_zero_counters(int* cnt_e, int* cnt_n) {
    int t = threadIdx.x;
    if (t < 16) { cnt_e[t] = 0; cnt_n[t] = 0; }
}

// ---------- edge prep: parent depth + hc mark + edge histogram ----------
__global__ void k_edge_pre(const int* __restrict__ parent, const int* __restrict__ depth,
                           unsigned char* __restrict__ hc, unsigned char* __restrict__ dp,
                           int* __restrict__ cnt_e) {
    __shared__ int lh[16];
    int t = threadIdx.x;
    if (t < 16) lh[t] = 0;
    __syncthreads();
    int e = blockIdx.x * 256 + t;
    if (e < NE) {
        int p = parent[e];
        hc[p] = 1;                       // racy same-value stores: fine
        int d = depth[p];                // always in [0, 14]
        dp[e] = (unsigned char)d;
        atomicAdd(&lh[d], 1);
    }
    __syncthreads();
    if (t < 16 && lh[t]) atomicAdd(&cnt_e[t], lh[t]);
}

// ---------- node prep: nd (bin = depth if internal else 15), zero h, node histogram ----------
__global__ void k_prep_n(const int* __restrict__ depth, const unsigned char* __restrict__ hc,
                         unsigned char* __restrict__ nd, float* __restrict__ h,
                         int* __restrict__ cnt_n) {
    __shared__ int lh[16];
    int t = threadIdx.x;
    if (t < 16) lh[t] = 0;
    __syncthreads();
    int i = blockIdx.x * 256 + t;
    int bin = 16;
    if (i < NN) {
        bin = hc[i] ? depth[i] : 15;     // internal depth in [0,14]; leaves -> 15
        nd[i] = (unsigned char)bin;
        atomicAdd(&lh[bin], 1);
        float* hr = h + (size_t)i * REC;
        #pragma unroll
        for (int j = 0; j < REC; ++j) hr[j] = 0.f;
    }
    __syncthreads();
    if (t < 16 && lh[t]) atomicAdd(&cnt_n[t], lh[t]);
}

// ---------- exclusive scan of the 16-bin histograms ----------
__global__ void k_scan(const int* __restrict__ cnt_e, const int* __restrict__ cnt_n,
                       int* __restrict__ off_e, int* __restrict__ cur_e,
                       int* __restrict__ off_n, int* __restrict__ cur_n) {
    if (threadIdx.x == 0 && blockIdx.x == 0) {
        int s = 0;
        for (int d = 0; d < 16; ++d) { off_e[d] = s; cur_e[d] = s; s += cnt_e[d]; }
        s = 0;
        for (int d = 0; d < 16; ++d) { off_n[d] = s; cur_n[d] = s; s += cnt_n[d]; }
    }
}

// ---------- scatter: counting-sort edges by parent depth ----------
__global__ void k_scatter_e(const unsigned char* __restrict__ dp, int* __restrict__ cur_e,
                            int* __restrict__ edge_list) {
    __shared__ int lh[16];
    __shared__ int base[16];
    int t = threadIdx.x;
    if (t < 16) lh[t] = 0;
    __syncthreads();
    int e = blockIdx.x * 256 + t;
    int d = 0, r = 0;
    bool live = (e < NE);
    if (live) { d = dp[e]; r = atomicAdd(&lh[d], 1); }
    __syncthreads();
    if (t < 16 && lh[t]) base[t] = atomicAdd(&cur_e[t], lh[t]);
    __syncthreads();
    if (live) edge_list[base[d] + r] = e;
}

// ---------- scatter: counting-sort nodes by bin (internal depth / leaf=15) ----------
__global__ void k_scatter_n(const unsigned char* __restrict__ nd, int* __restrict__ cur_n,
                            int* __restrict__ node_list) {
    __shared__ int lh[16];
    __shared__ int base[16];
    int t = threadIdx.x;
    if (t < 16) lh[t] = 0;
    __syncthreads();
    int i = blockIdx.x * 256 + t;
    int d = 0, r = 0;
    bool live = (i < NN);
    if (live) { d = nd[i]; r = atomicAdd(&lh[d], 1); }
    __syncthreads();
    if (t < 16 && lh[t]) base[t] = atomicAdd(&cur_n[t], lh[t]);
    __syncthreads();
    if (live) node_list[base[d] + r] = i;
}

// ---------- leaf MLP over compacted leaf list (bin 15) ----------
__global__ void k_leaf_c(const int* __restrict__ off_n, const int* __restrict__ cnt_n,
                         const int* __restrict__ node_list,
                         const float* __restrict__ atom,
                         const float* __restrict__ w1, const float* __restrict__ b1,
                         const float* __restrict__ w2, const float* __restrict__ b2,
                         float* __restrict__ h) {
    int n = cnt_n[15];
    int base = off_n[15];
    for (int t = blockIdx.x * blockDim.x + threadIdx.x; t < n; t += gridDim.x * blockDim.x) {
        int i = node_list[base + t];
        float a[ATOM];
        #pragma unroll
        for (int k = 0; k < ATOM; ++k) a[k] = atom[(size_t)i * ATOM + k];
        float hid[HID];
        #pragma unroll
        for (int j = 0; j < HID; ++j) hid[j] = b1[j];
        for (int k = 0; k < ATOM; ++k) {
            float ak = a[k];
            #pragma unroll
            for (int j = 0; j < HID; ++j) hid[j] += ak * w1[k * HID + j];
        }
        #pragma unroll
        for (int j = 0; j < HID; ++j) hid[j] = leaky(hid[j]);
        float o[REC];
        #pragma unroll
        for (int j = 0; j < REC; ++j) o[j] = b2[j];
        for (int k = 0; k < HID; ++k) {
            float hk = hid[k];
            #pragma unroll
            for (int j = 0; j < REC; ++j) o[j] += hk * w2[k * REC + j];
        }
        float* hr = h + (size_t)i * REC;
        #pragma unroll
        for (int j = 0; j < REC; ++j) hr[j] = leaky(o[j]);
    }
}

// ---------- per-depth edge kernel over compacted list ----------
__global__ void k_edge_c(int d, const int* __restrict__ off_e, const int* __restrict__ cnt_e,
                         const int* __restrict__ edge_list,
                         const int* __restrict__ parent, const int* __restrict__ child,
                         const float* __restrict__ bond,
                         const float* __restrict__ iw, const float* __restrict__ ib,
                         float* __restrict__ h) {
    int n = cnt_e[d];
    int base = off_e[d];
    for (int t = blockIdx.x * blockDim.x + threadIdx.x; t < n; t += gridDim.x * blockDim.x) {
        int e = edge_list[base + t];
        int p = parent[e], c = child[e];
        float x[BOND + REC];
        x[0] = bond[(size_t)e * BOND + 0];
        x[1] = bond[(size_t)e * BOND + 1];
        x[2] = bond[(size_t)e * BOND + 2];
        const float* ch = h + (size_t)c * REC;
        #pragma unroll
        for (int k = 0; k < REC; ++k) x[BOND + k] = ch[k];
        float m[INNER];
        #pragma unroll
        for (int j = 0; j < INNER; ++j) m[j] = ib[j];
        for (int k = 0; k < BOND + REC; ++k) {
            float xk = x[k];
            #pragma unroll
            for (int j = 0; j < INNER; ++j) m[j] += xk * iw[k * INNER + j];
        }
        float* pr = h + (size_t)p * REC;
        #pragma unroll
        for (int j = 0; j < INNER; ++j) atomicAdd(&pr[j], leaky(m[j]));
    }
}

// ---------- per-depth node MLP over compacted list ----------
__global__ void k_node_c(int d, const int* __restrict__ off_n, const int* __restrict__ cnt_n,
                         const int* __restrict__ node_list,
                         const float* __restrict__ atom,
                         const float* __restrict__ w1, const float* __restrict__ b1,
                         const float* __restrict__ w2, const float* __restrict__ b2,
                         float* __restrict__ h) {
    int n = cnt_n[d];
    int base = off_n[d];
    for (int t = blockIdx.x * blockDim.x + threadIdx.x; t < n; t += gridDim.x * blockDim.x) {
        int i = node_list[base + t];
        float x[ATOM + INNER];
        #pragma unroll
        for (int k = 0; k < ATOM; ++k) x[k] = atom[(size_t)i * ATOM + k];
        float* hrow = h + (size_t)i * REC;
        #pragma unroll
        for (int k = 0; k < INNER; ++k) x[ATOM + k] = hrow[k];
        float hid[HID];
        #pragma unroll
        for (int j = 0; j < HID; ++j) hid[j] = b1[j];
        for (int k = 0; k < ATOM + INNER; ++k) {
            float xk = x[k];
            #pragma unroll
            for (int j = 0; j < HID; ++j) hid[j] += xk * w1[k * HID + j];
        }
        #pragma unroll
        for (int j = 0; j < HID; ++j) hid[j] = leaky(hid[j]);
        float o[REC];
        #pragma unroll
        for (int j = 0; j < REC; ++j) o[j] = b2[j];
        for (int k = 0; k < HID; ++k) {
            float hk = hid[k];
            #pragma unroll
            for (int j = 0; j < REC; ++j) o[j] += hk * w2[k * REC + j];
        }
        #pragma unroll
        for (int j = 0; j < REC; ++j) hrow[j] = leaky(o[j]);
    }
}

// ---------- readout ----------
__global__ void k_zero_g(float* g) {
    int i = blockIdx.x * 256 + threadIdx.x;
    if (i < NG * REC) g[i] = 0.f;
}

__global__ void k_root(const float* __restrict__ isr, const int* __restrict__ gid,
                       const float* __restrict__ h, float* __restrict__ g) {
    int i = blockIdx.x * 256 + threadIdx.x;
    if (i >= NN) return;
    float r = isr[i];
    if (r == 0.f) return;
    int t = gid[i];
    const float* hr = h + (size_t)i * REC;
    float* gr = g + (size_t)t * REC;
    #pragma unroll
    for (int j = 0; j < REC; ++j) atomicAdd(&gr[j], hr[j] * r);
}

__global__ void k_out(const float* __restrict__ g,
                      const float* __restrict__ w1, const float* __restrict__ b1,
                      const float* __restrict__ w2, const float* __restrict__ b2,
                      float* __restrict__ out) {
    int t = blockIdx.x * 256 + threadIdx.x;
    if (t >= NG) return;
    const float* gv = g + (size_t)t * REC;
    float gl[REC];
    #pragma unroll
    for (int k = 0; k < REC; ++k) gl[k] = gv[k];
    float acc = b2[0];
    for (int j = 0; j < OHID; ++j) {
        float s = b1[j];
        #pragma unroll
        for (int k = 0; k < REC; ++k) s += gl[k] * w1[k * OHID + j];
        acc += tanhf(s) * w2[j];
    }
    out[t] = acc;
}

extern "C" void kernel_launch(void* const* d_in, const int* in_sizes, int n_in,
                              void* d_out, int out_size, void* d_ws, size_t ws_size,
                              hipStream_t stream) {
    const float* atom    = (const float*)d_in[0];
    const float* bond    = (const float*)d_in[1];
    const int*   parent  = (const int*)d_in[2];
    const int*   child   = (const int*)d_in[3];
    const int*   depth   = (const int*)d_in[4];
    const int*   gid     = (const int*)d_in[5];
    const float* isr     = (const float*)d_in[6];
    const float* inner_w = (const float*)d_in[7];
    const float* inner_b = (const float*)d_in[8];
    const float* net_w1  = (const float*)d_in[9];
    const float* net_b1  = (const float*)d_in[10];
    const float* net_w2  = (const float*)d_in[11];
    const float* net_b2  = (const float*)d_in[12];
    const float* net0_w1 = (const float*)d_in[13];
    const float* net0_b1 = (const float*)d_in[14];
    const float* net0_w2 = (const float*)d_in[15];
    const float* net0_b2 = (const float*)d_in[16];
    const float* out_w1  = (const float*)d_in[17];
    const float* out_b1  = (const float*)d_in[18];
    const float* out_w2  = (const float*)d_in[19];
    const float* out_b2  = (const float*)d_in[20];
    float* out = (float*)d_out;

    char* ws = (char*)d_ws;
    size_t o = 0;
    float* h = (float*)(ws + o);          o += (size_t)NN * REC * 4;   // 83.9 MB
    float* g = (float*)(ws + o);          o += (size_t)NG * REC * 4;   // 1.3 MB
    int* edge_list = (int*)(ws + o);      o += (size_t)NE * 4;         // 3.93 MB
    int* node_list = (int*)(ws + o);      o += (size_t)NN * 4;         // 4.19 MB
    int* cnt_e = (int*)(ws + o);          o += 16 * 4;
    int* off_e = (int*)(ws + o);          o += 16 * 4;
    int* cur_e = (int*)(ws + o);          o += 16 * 4;
    int* cnt_n = (int*)(ws + o);          o += 16 * 4;
    int* off_n = (int*)(ws + o);          o += 16 * 4;
    int* cur_n = (int*)(ws + o);          o += 16 * 4;
    unsigned char* dp = (unsigned char*)(ws + o); o += (size_t)NE;     // 0.98 MB
    unsigned char* nd = (unsigned char*)(ws + o); o += (size_t)NN;     // 1.05 MB
    unsigned char* hc = (unsigned char*)(ws + o); o += (size_t)NN;     // 1.05 MB

    dim3 B(256);
    int nbN = (NN + 255) / 256;
    int nbE = (NE + 255) / 256;

    k_init_hc<<<nbN, B, 0, stream>>>(hc);
    k_zero_counters<<<1, 64, 0, stream>>>(cnt_e, cnt_n);
    k_edge_pre<<<nbE, B, 0, stream>>>(parent, depth, hc, dp, cnt_e);
    k_prep_n<<<nbN, B, 0, stream>>>(depth, hc, nd, h, cnt_n);
    k_scan<<<1, 64, 0, stream>>>(cnt_e, cnt_n, off_e, cur_e, off_n, cur_n);
    k_scatter_e<<<nbE, B, 0, stream>>>(dp, cur_e, edge_list);
    k_scatter_n<<<nbN, B, 0, stream>>>(nd, cur_n, node_list);
    k_leaf_c<<<1024, B, 0, stream>>>(off_n, cnt_n, node_list, atom,
                                     net0_w1, net0_b1, net0_w2, net0_b2, h);
    for (int d = MAXD - 2; d >= 0; --d) {
        k_edge_c<<<512, B, 0, stream>>>(d, off_e, cnt_e, edge_list, parent, child, bond,
                                        inner_w, inner_b, h);
        k_node_c<<<512, B, 0, stream>>>(d, off_n, cnt_n, node_list, atom,
                                        net_w1, net_b1, net_w2, net_b2, h);
    }
    k_zero_g<<<(NG * REC + 255) / 256, B, 0, stream>>>(g);
    k_root<<<nbN, B, 0, stream>>>(isr, gid, h, g);
    k_out<<<(NG + 255) / 256, B, 0, stream>>>(g, out_w1, out_b1, out_w2, out_b2, out);
}

// Round 3
// 3951.677 us; speedup vs baseline: 1.5379x; 1.0524x over previous
//
#include <hip/hip_runtime.h>

#define ATOM  14
#define BOND  3
#define INNER 20
#define HID   34
#define REC   20
#define OHID  25
#define NN    1048576
#define NE    983040
#define NG    16384
#define MAXD  16
#define NBIN  32

__device__ __forceinline__ float leaky(float x) { return x >= 0.f ? x : 0.01f * x; }

// ---------- prep ----------
__global__ void k_init(unsigned char* hc, int* pe, int* cnt) {
    int i = blockIdx.x * 256 + threadIdx.x;
    if (i < NN) { hc[i] = 0; pe[i] = -1; }
    if (i < NBIN) cnt[i] = 0;
}

// mark parents; record each child's (unique) incoming edge
__global__ void k_mark(const int* __restrict__ parent, const int* __restrict__ child,
                       unsigned char* __restrict__ hc, int* __restrict__ pe) {
    int e = blockIdx.x * 256 + threadIdx.x;
    if (e >= NE) return;
    hc[parent[e]] = 1;     // racy same-value: fine
    pe[child[e]] = e;      // child unique per edge (replace=False)
}

__device__ __forceinline__ int node_bin(int d, unsigned char c) {
    return (c && d < 15) ? d : 16 + d;   // internal by depth; leaf-like 16+depth
}

__global__ void k_hist(const int* __restrict__ depth, const unsigned char* __restrict__ hc,
                       int* __restrict__ cnt) {
    __shared__ int lh[NBIN];
    int t = threadIdx.x;
    if (t < NBIN) lh[t] = 0;
    __syncthreads();
    int i = blockIdx.x * 256 + t;
    if (i < NN) atomicAdd(&lh[node_bin(depth[i], hc[i])], 1);
    __syncthreads();
    if (t < NBIN && lh[t]) atomicAdd(&cnt[t], lh[t]);
}

__global__ void k_scan(const int* __restrict__ cnt, int* __restrict__ off, int* __restrict__ cur) {
    if (threadIdx.x == 0 && blockIdx.x == 0) {
        int s = 0;
        for (int d = 0; d < NBIN; ++d) { off[d] = s; cur[d] = s; s += cnt[d]; }
        off[NBIN] = s;   // == NN
    }
}

// scatter into sorted position space; build inverse perm; zero internal h rows
__global__ void k_scatter(const int* __restrict__ depth, const unsigned char* __restrict__ hc,
                          int* __restrict__ cur, int* __restrict__ node_list,
                          int* __restrict__ inv, float* __restrict__ h) {
    __shared__ int lh[NBIN];
    __shared__ int base[NBIN];
    int t = threadIdx.x;
    if (t < NBIN) lh[t] = 0;
    __syncthreads();
    int i = blockIdx.x * 256 + t;
    int b = 0, r = 0;
    bool live = (i < NN);
    if (live) { b = node_bin(depth[i], hc[i]); r = atomicAdd(&lh[b], 1); }
    __syncthreads();
    if (t < NBIN && lh[t]) base[t] = atomicAdd(&cur[t], lh[t]);
    __syncthreads();
    if (live) {
        int pos = base[b] + r;
        node_list[pos] = i;
        inv[i] = pos;
        if (b < 16) {                       // internal: accumulation target
            float4* hr = (float4*)(h + (size_t)pos * REC);
            float4 z = make_float4(0.f, 0.f, 0.f, 0.f);
            #pragma unroll
            for (int j = 0; j < 5; ++j) hr[j] = z;
        }
    }
}

// per-position parent position (or -1), breaking the scatter chain for level kernels
__global__ void k_edge_meta(const int* __restrict__ node_list, const int* __restrict__ pe,
                            const int* __restrict__ parent, const int* __restrict__ inv,
                            const int* __restrict__ off, int* __restrict__ pp_s) {
    int pos = blockIdx.x * 256 + threadIdx.x;
    if (pos >= NN) return;
    int internal_end = off[16];
    int i = node_list[pos];
    int e = pe[i];
    int pp = -1;
    if (e >= 0) {
        int q = inv[parent[e]];
        if (q < internal_end) pp = q;       // only message true internal parents
    }
    pp_s[pos] = pp;
}

// ---------- fused compute: own MLP + outgoing message ----------
__device__ __forceinline__ void send_msg(const float* __restrict__ hown,
                                         const float* __restrict__ bond, int e,
                                         const float* __restrict__ iw,
                                         const float* __restrict__ ib,
                                         float* __restrict__ dst) {
    float m[INNER];
    #pragma unroll
    for (int j = 0; j < INNER; ++j) m[j] = ib[j];
    const float* br = bond + (size_t)e * BOND;
    #pragma unroll
    for (int k = 0; k < BOND; ++k) {
        float xk = br[k];
        #pragma unroll
        for (int j = 0; j < INNER; ++j) m[j] += xk * iw[k * INNER + j];
    }
    #pragma unroll
    for (int k = 0; k < REC; ++k) {
        float xk = hown[k];
        #pragma unroll
        for (int j = 0; j < INNER; ++j) m[j] += xk * iw[(BOND + k) * INNER + j];
    }
    #pragma unroll
    for (int j = 0; j < INNER; ++j) atomicAdd(&dst[j], leaky(m[j]));
}

// leaf-like nodes: positions [off[16], NN): net0 MLP + message
__global__ void k_leaf(const int* __restrict__ off, const int* __restrict__ node_list,
                       const int* __restrict__ pe, const int* __restrict__ pp_s,
                       const float* __restrict__ atom, const float* __restrict__ bond,
                       const float* __restrict__ w1, const float* __restrict__ b1,
                       const float* __restrict__ w2, const float* __restrict__ b2,
                       const float* __restrict__ iw, const float* __restrict__ ib,
                       float* __restrict__ h) {
    int p0 = off[16];
    for (int pos = p0 + blockIdx.x * blockDim.x + threadIdx.x; pos < NN;
         pos += gridDim.x * blockDim.x) {
        int i = node_list[pos];
        const float2* a2 = (const float2*)(atom + (size_t)i * ATOM);
        float a[ATOM];
        #pragma unroll
        for (int k = 0; k < 7; ++k) { float2 v = a2[k]; a[2*k] = v.x; a[2*k+1] = v.y; }
        float hid[HID];
        #pragma unroll
        for (int j = 0; j < HID; ++j) hid[j] = b1[j];
        for (int k = 0; k < ATOM; ++k) {
            float ak = a[k];
            #pragma unroll
            for (int j = 0; j < HID; ++j) hid[j] += ak * w1[k * HID + j];
        }
        #pragma unroll
        for (int j = 0; j < HID; ++j) hid[j] = leaky(hid[j]);
        float o[REC];
        #pragma unroll
        for (int j = 0; j < REC; ++j) o[j] = b2[j];
        for (int k = 0; k < HID; ++k) {
            float hk = hid[k];
            #pragma unroll
            for (int j = 0; j < REC; ++j) o[j] += hk * w2[k * REC + j];
        }
        #pragma unroll
        for (int j = 0; j < REC; ++j) o[j] = leaky(o[j]);
        float4* hr = (float4*)(h + (size_t)pos * REC);
        #pragma unroll
        for (int j = 0; j < 5; ++j)
            hr[j] = make_float4(o[4*j], o[4*j+1], o[4*j+2], o[4*j+3]);
        int pp = pp_s[pos];
        if (pp >= 0) send_msg(o, bond, pe[i], iw, ib, h + (size_t)pp * REC);
    }
}

// internal nodes at depth d: positions [off[d], off[d+1]): net MLP + message
__global__ void k_level(int d, const int* __restrict__ off, const int* __restrict__ node_list,
                        const int* __restrict__ pe, const int* __restrict__ pp_s,
                        const float* __restrict__ atom, const float* __restrict__ bond,
                        const float* __restrict__ w1, const float* __restrict__ b1,
                        const float* __restrict__ w2, const float* __restrict__ b2,
                        const float* __restrict__ iw, const float* __restrict__ ib,
                        float* __restrict__ h) {
    int p0 = off[d], p1 = off[d + 1];
    for (int pos = p0 + blockIdx.x * blockDim.x + threadIdx.x; pos < p1;
         pos += gridDim.x * blockDim.x) {
        int i = node_list[pos];
        const float2* a2 = (const float2*)(atom + (size_t)i * ATOM);
        float x[ATOM + INNER];
        #pragma unroll
        for (int k = 0; k < 7; ++k) { float2 v = a2[k]; x[2*k] = v.x; x[2*k+1] = v.y; }
        float4* hr = (float4*)(h + (size_t)pos * REC);
        #pragma unroll
        for (int j = 0; j < 5; ++j) {
            float4 v = hr[j];
            x[ATOM + 4*j] = v.x; x[ATOM + 4*j+1] = v.y;
            x[ATOM + 4*j+2] = v.z; x[ATOM + 4*j+3] = v.w;
        }
        float hid[HID];
        #pragma unroll
        for (int j = 0; j < HID; ++j) hid[j] = b1[j];
        for (int k = 0; k < ATOM + INNER; ++k) {
            float xk = x[k];
            #pragma unroll
            for (int j = 0; j < HID; ++j) hid[j] += xk * w1[k * HID + j];
        }
        #pragma unroll
        for (int j = 0; j < HID; ++j) hid[j] = leaky(hid[j]);
        float o[REC];
        #pragma unroll
        for (int j = 0; j < REC; ++j) o[j] = b2[j];
        for (int k = 0; k < HID; ++k) {
            float hk = hid[k];
            #pragma unroll
            for (int j = 0; j < REC; ++j) o[j] += hk * w2[k * REC + j];
        }
        #pragma unroll
        for (int j = 0; j < REC; ++j) o[j] = leaky(o[j]);
        #pragma unroll
        for (int j = 0; j < 5; ++j)
            hr[j] = make_float4(o[4*j], o[4*j+1], o[4*j+2], o[4*j+3]);
        int pp = pp_s[pos];
        if (pp >= 0) send_msg(o, bond, pe[i], iw, ib, h + (size_t)pp * REC);
    }
}

// ---------- readout ----------
__global__ void k_zero_g(float* g) {
    int i = blockIdx.x * 256 + threadIdx.x;
    if (i < NG * REC) g[i] = 0.f;
}

__global__ void k_root(const float* __restrict__ isr, const int* __restrict__ gid,
                       const int* __restrict__ inv, const float* __restrict__ h,
                       float* __restrict__ g) {
    int i = blockIdx.x * 256 + threadIdx.x;
    if (i >= NN) return;
    float r = isr[i];
    if (r == 0.f) return;
    const float* hr = h + (size_t)inv[i] * REC;
    float* gr = g + (size_t)gid[i] * REC;
    #pragma unroll
    for (int j = 0; j < REC; ++j) atomicAdd(&gr[j], hr[j] * r);
}

__global__ void k_out(const float* __restrict__ g,
                      const float* __restrict__ w1, const float* __restrict__ b1,
                      const float* __restrict__ w2, const float* __restrict__ b2,
                      float* __restrict__ out) {
    int t = blockIdx.x * 256 + threadIdx.x;
    if (t >= NG) return;
    const float* gv = g + (size_t)t * REC;
    float gl[REC];
    #pragma unroll
    for (int k = 0; k < REC; ++k) gl[k] = gv[k];
    float acc = b2[0];
    for (int j = 0; j < OHID; ++j) {
        float s = b1[j];
        #pragma unroll
        for (int k = 0; k < REC; ++k) s += gl[k] * w1[k * OHID + j];
        acc += tanhf(s) * w2[j];
    }
    out[t] = acc;
}

extern "C" void kernel_launch(void* const* d_in, const int* in_sizes, int n_in,
                              void* d_out, int out_size, void* d_ws, size_t ws_size,
                              hipStream_t stream) {
    const float* atom    = (const float*)d_in[0];
    const float* bond    = (const float*)d_in[1];
    const int*   parent  = (const int*)d_in[2];
    const int*   child   = (const int*)d_in[3];
    const int*   depth   = (const int*)d_in[4];
    const int*   gid     = (const int*)d_in[5];
    const float* isr     = (const float*)d_in[6];
    const float* inner_w = (const float*)d_in[7];
    const float* inner_b = (const float*)d_in[8];
    const float* net_w1  = (const float*)d_in[9];
    const float* net_b1  = (const float*)d_in[10];
    const float* net_w2  = (const float*)d_in[11];
    const float* net_b2  = (const float*)d_in[12];
    const float* net0_w1 = (const float*)d_in[13];
    const float* net0_b1 = (const float*)d_in[14];
    const float* net0_w2 = (const float*)d_in[15];
    const float* net0_b2 = (const float*)d_in[16];
    const float* out_w1  = (const float*)d_in[17];
    const float* out_b1  = (const float*)d_in[18];
    const float* out_w2  = (const float*)d_in[19];
    const float* out_b2  = (const float*)d_in[20];
    float* out = (float*)d_out;

    char* ws = (char*)d_ws;
    size_t o = 0;
    float* h_s      = (float*)(ws + o);  o += (size_t)NN * REC * 4;   // 83.9 MB
    float* g        = (float*)(ws + o);  o += (size_t)NG * REC * 4;   // 1.3 MB
    int* node_list  = (int*)(ws + o);    o += (size_t)NN * 4;         // 4.2 MB
    int* inv        = (int*)(ws + o);    o += (size_t)NN * 4;         // 4.2 MB
    int* pe         = (int*)(ws + o);    o += (size_t)NN * 4;         // 4.2 MB
    int* pp_s       = (int*)(ws + o);    o += (size_t)NN * 4;         // 4.2 MB
    int* cnt        = (int*)(ws + o);    o += NBIN * 4;
    int* off        = (int*)(ws + o);    o += (NBIN + 1) * 4;
    int* cur        = (int*)(ws + o);    o += NBIN * 4;
    unsigned char* hc = (unsigned char*)(ws + o); o += (size_t)NN;    // 1.0 MB
    // total ~103 MB

    dim3 B(256);
    int nbN = (NN + 255) / 256;
    int nbE = (NE + 255) / 256;

    k_init<<<nbN, B, 0, stream>>>(hc, pe, cnt);
    k_mark<<<nbE, B, 0, stream>>>(parent, child, hc, pe);
    k_hist<<<nbN, B, 0, stream>>>(depth, hc, cnt);
    k_scan<<<1, 64, 0, stream>>>(cnt, off, cur);
    k_scatter<<<nbN, B, 0, stream>>>(depth, hc, cur, node_list, inv, h_s);
    k_edge_meta<<<nbN, B, 0, stream>>>(node_list, pe, parent, inv, off, pp_s);
    k_leaf<<<1024, B, 0, stream>>>(off, node_list, pe, pp_s, atom, bond,
                                   net0_w1, net0_b1, net0_w2, net0_b2,
                                   inner_w, inner_b, h_s);
    for (int d = MAXD - 2; d >= 0; --d)
        k_level<<<512, B, 0, stream>>>(d, off, node_list, pe, pp_s, atom, bond,
                                       net_w1, net_b1, net_w2, net_b2,
                                       inner_w, inner_b, h_s);
    k_zero_g<<<(NG * REC + 255) / 256, B, 0, stream>>>(g);
    k_root<<<nbN, B, 0, stream>>>(isr, gid, inv, h_s, g);
    k_out<<<(NG + 255) / 256, B, 0, stream>>>(g, out_w1, out_b1, out_w2, out_b2, out);
}

// Round 4
// 3519.886 us; speedup vs baseline: 1.7266x; 1.1227x over previous
//
#include <hip/hip_runtime.h>

#define ATOM  14
#define BOND  3
#define INNER 20
#define HID   34
#define REC   20
#define OHID  25
#define NN    1048576
#define NE    983040
#define NG    16384
#define MAXD  16
#define NBIN  32

#define SCAN_B 512     // NN / 2048
#define SCAN_T 256
#define SCAN_E 8       // 2048 per block

__device__ __forceinline__ float leaky(float x) { return x >= 0.f ? x : 0.01f * x; }

// ---------- prep ----------
__global__ void k_init(unsigned char* hc, int* cnt) {
    int i = blockIdx.x * 256 + threadIdx.x;
    if (i < NN) hc[i] = 0;
    if (i < NBIN) cnt[i] = 0;
}

__global__ void k_mark(const int* __restrict__ parent, unsigned char* __restrict__ hc) {
    int e = blockIdx.x * 256 + threadIdx.x;
    if (e < NE) hc[parent[e]] = 1;   // racy same-value: fine
}

__device__ __forceinline__ int node_bin(int d, unsigned char c) {
    return (c && d < 15) ? d : 16 + d;   // internal by depth; leaf-like 16+depth
}

__global__ void k_hist(const int* __restrict__ depth, const unsigned char* __restrict__ hc,
                       int* __restrict__ cnt) {
    __shared__ int lh[NBIN];
    int t = threadIdx.x;
    if (t < NBIN) lh[t] = 0;
    __syncthreads();
    int i = blockIdx.x * 256 + t;
    if (i < NN) atomicAdd(&lh[node_bin(depth[i], hc[i])], 1);
    __syncthreads();
    if (t < NBIN && lh[t]) atomicAdd(&cnt[t], lh[t]);
}

__global__ void k_scan(const int* __restrict__ cnt, int* __restrict__ off, int* __restrict__ cur) {
    if (threadIdx.x == 0 && blockIdx.x == 0) {
        int s = 0;
        for (int d = 0; d < NBIN; ++d) { off[d] = s; cur[d] = s; s += cnt[d]; }
        off[NBIN] = s;
    }
}

__global__ void k_scatter(const int* __restrict__ depth, const unsigned char* __restrict__ hc,
                          int* __restrict__ cur, int* __restrict__ node_list,
                          int* __restrict__ inv) {
    __shared__ int lh[NBIN];
    __shared__ int base[NBIN];
    int t = threadIdx.x;
    if (t < NBIN) lh[t] = 0;
    __syncthreads();
    int i = blockIdx.x * 256 + t;
    int b = 0, r = 0;
    bool live = (i < NN);
    if (live) { b = node_bin(depth[i], hc[i]); r = atomicAdd(&lh[b], 1); }
    __syncthreads();
    if (t < NBIN && lh[t]) base[t] = atomicAdd(&cur[t], lh[t]);
    __syncthreads();
    if (live) {
        int pos = base[b] + r;
        node_list[pos] = i;
        inv[i] = pos;
    }
}

// ---------- CSR build (position space) ----------
__global__ void k_zero_cntp(int* cnt_p) {
    int i = blockIdx.x * 256 + threadIdx.x;
    if (i < NN) cnt_p[i] = 0;
}

__global__ void k_histp(const int* __restrict__ parent, const int* __restrict__ inv,
                        int* __restrict__ cnt_p) {
    int e = blockIdx.x * 256 + threadIdx.x;
    if (e < NE) atomicAdd(&cnt_p[inv[parent[e]]], 1);
}

__global__ void k_scanA(const int* __restrict__ cnt_p, int* __restrict__ row_ptr,
                        int* __restrict__ bsum) {
    __shared__ int s[SCAN_T];
    int b = blockIdx.x, t = threadIdx.x;
    int base = b * SCAN_T * SCAN_E + t * SCAN_E;
    int v[SCAN_E];
    int sum = 0;
    #pragma unroll
    for (int k = 0; k < SCAN_E; ++k) { v[k] = cnt_p[base + k]; sum += v[k]; }
    s[t] = sum;
    __syncthreads();
    for (int ofs = 1; ofs < SCAN_T; ofs <<= 1) {
        int x = (t >= ofs) ? s[t - ofs] : 0;
        __syncthreads();
        s[t] += x;
        __syncthreads();
    }
    int run = s[t] - sum;       // exclusive prefix within block
    #pragma unroll
    for (int k = 0; k < SCAN_E; ++k) { row_ptr[base + k] = run; run += v[k]; }
    if (t == SCAN_T - 1) bsum[b] = s[t];
}

__global__ void k_scanB(const int* __restrict__ bsum, int* __restrict__ boff,
                        int* __restrict__ row_ptr) {
    __shared__ int s[SCAN_B];
    int t = threadIdx.x;          // 512 threads
    int v = bsum[t];
    s[t] = v;
    __syncthreads();
    for (int ofs = 1; ofs < SCAN_B; ofs <<= 1) {
        int x = (t >= ofs) ? s[t - ofs] : 0;
        __syncthreads();
        s[t] += x;
        __syncthreads();
    }
    boff[t] = s[t] - v;
    if (t == SCAN_B - 1) row_ptr[NN] = s[t];
}

__global__ void k_scanC(int* __restrict__ row_ptr, const int* __restrict__ boff,
                        int* __restrict__ cnt_p) {
    int i = blockIdx.x * 256 + threadIdx.x;
    if (i < NN) { row_ptr[i] += boff[i >> 11]; cnt_p[i] = 0; }
}

__global__ void k_adj(const int* __restrict__ parent, const int* __restrict__ child,
                      const float* __restrict__ bond, const int* __restrict__ inv,
                      const int* __restrict__ row_ptr, int* __restrict__ cnt_p,
                      float4* __restrict__ adj) {
    int e = blockIdx.x * 256 + threadIdx.x;
    if (e >= NE) return;
    int q = inv[parent[e]];
    int c = inv[child[e]];
    int r = atomicAdd(&cnt_p[q], 1);
    const float* br = bond + (size_t)e * BOND;
    adj[row_ptr[q] + r] = make_float4(__int_as_float(c), br[0], br[1], br[2]);
}

// ---------- compute ----------
// leaf-like nodes: positions [off[16], NN): net0 MLP, contiguous h write
__global__ void k_leaf(const int* __restrict__ off, const int* __restrict__ node_list,
                       const float* __restrict__ atom,
                       const float* __restrict__ w1, const float* __restrict__ b1,
                       const float* __restrict__ w2, const float* __restrict__ b2,
                       float* __restrict__ h) {
    int p0 = off[16];
    for (int pos = p0 + blockIdx.x * blockDim.x + threadIdx.x; pos < NN;
         pos += gridDim.x * blockDim.x) {
        int i = node_list[pos];
        const float2* a2 = (const float2*)(atom + (size_t)i * ATOM);
        float a[ATOM];
        #pragma unroll
        for (int k = 0; k < 7; ++k) { float2 v = a2[k]; a[2*k] = v.x; a[2*k+1] = v.y; }
        float hid[HID];
        #pragma unroll
        for (int j = 0; j < HID; ++j) hid[j] = b1[j];
        for (int k = 0; k < ATOM; ++k) {
            float ak = a[k];
            #pragma unroll
            for (int j = 0; j < HID; ++j) hid[j] += ak * w1[k * HID + j];
        }
        #pragma unroll
        for (int j = 0; j < HID; ++j) hid[j] = leaky(hid[j]);
        float o[REC];
        #pragma unroll
        for (int j = 0; j < REC; ++j) o[j] = b2[j];
        for (int k = 0; k < HID; ++k) {
            float hk = hid[k];
            #pragma unroll
            for (int j = 0; j < REC; ++j) o[j] += hk * w2[k * REC + j];
        }
        float4* hr = (float4*)(h + (size_t)pos * REC);
        #pragma unroll
        for (int j = 0; j < 5; ++j)
            hr[j] = make_float4(leaky(o[4*j]), leaky(o[4*j+1]), leaky(o[4*j+2]), leaky(o[4*j+3]));
    }
}

// internal nodes at depth d: gather children messages from CSR, MLP, write h
__global__ void k_level(int d, const int* __restrict__ off, const int* __restrict__ node_list,
                        const int* __restrict__ row_ptr, const float4* __restrict__ adj,
                        const float* __restrict__ atom,
                        const float* __restrict__ w1, const float* __restrict__ b1,
                        const float* __restrict__ w2, const float* __restrict__ b2,
                        const float* __restrict__ iw, const float* __restrict__ ib,
                        float* __restrict__ h) {
    int p0 = off[d], p1 = off[d + 1];
    for (int pos = p0 + blockIdx.x * blockDim.x + threadIdx.x; pos < p1;
         pos += gridDim.x * blockDim.x) {
        int r0 = row_ptr[pos], r1 = row_ptr[pos + 1];
        float isum[INNER];
        #pragma unroll
        for (int j = 0; j < INNER; ++j) isum[j] = 0.f;
        for (int r = r0; r < r1; ++r) {
            float4 a4 = adj[r];
            int cpos = __float_as_int(a4.x);
            float m[INNER];
            #pragma unroll
            for (int j = 0; j < INNER; ++j)
                m[j] = ib[j] + a4.y * iw[0 * INNER + j] + a4.z * iw[1 * INNER + j]
                             + a4.w * iw[2 * INNER + j];
            const float4* ch = (const float4*)(h + (size_t)cpos * REC);
            #pragma unroll
            for (int q = 0; q < 5; ++q) {
                float4 cv = ch[q];
                float c0 = cv.x, c1 = cv.y, c2 = cv.z, c3 = cv.w;
                #pragma unroll
                for (int j = 0; j < INNER; ++j) {
                    m[j] += c0 * iw[(BOND + 4*q + 0) * INNER + j];
                    m[j] += c1 * iw[(BOND + 4*q + 1) * INNER + j];
                    m[j] += c2 * iw[(BOND + 4*q + 2) * INNER + j];
                    m[j] += c3 * iw[(BOND + 4*q + 3) * INNER + j];
                }
            }
            #pragma unroll
            for (int j = 0; j < INNER; ++j) isum[j] += leaky(m[j]);
        }
        int i = node_list[pos];
        const float2* a2 = (const float2*)(atom + (size_t)i * ATOM);
        float x[ATOM + INNER];
        #pragma unroll
        for (int k = 0; k < 7; ++k) { float2 v = a2[k]; x[2*k] = v.x; x[2*k+1] = v.y; }
        #pragma unroll
        for (int k = 0; k < INNER; ++k) x[ATOM + k] = isum[k];
        float hid[HID];
        #pragma unroll
        for (int j = 0; j < HID; ++j) hid[j] = b1[j];
        for (int k = 0; k < ATOM + INNER; ++k) {
            float xk = x[k];
            #pragma unroll
            for (int j = 0; j < HID; ++j) hid[j] += xk * w1[k * HID + j];
        }
        #pragma unroll
        for (int j = 0; j < HID; ++j) hid[j] = leaky(hid[j]);
        float o[REC];
        #pragma unroll
        for (int j = 0; j < REC; ++j) o[j] = b2[j];
        for (int k = 0; k < HID; ++k) {
            float hk = hid[k];
            #pragma unroll
            for (int j = 0; j < REC; ++j) o[j] += hk * w2[k * REC + j];
        }
        float4* hr = (float4*)(h + (size_t)pos * REC);
        #pragma unroll
        for (int j = 0; j < 5; ++j)
            hr[j] = make_float4(leaky(o[4*j]), leaky(o[4*j+1]), leaky(o[4*j+2]), leaky(o[4*j+3]));
    }
}

// ---------- readout ----------
__global__ void k_zero_g(float* g) {
    int i = blockIdx.x * 256 + threadIdx.x;
    if (i < NG * REC) g[i] = 0.f;
}

__global__ void k_root(const float* __restrict__ isr, const int* __restrict__ gid,
                       const int* __restrict__ inv, const float* __restrict__ h,
                       float* __restrict__ g) {
    int i = blockIdx.x * 256 + threadIdx.x;
    if (i >= NN) return;
    float r = isr[i];
    if (r == 0.f) return;
    const float* hr = h + (size_t)inv[i] * REC;
    float* gr = g + (size_t)gid[i] * REC;
    #pragma unroll
    for (int j = 0; j < REC; ++j) atomicAdd(&gr[j], hr[j] * r);
}

__global__ void k_out(const float* __restrict__ g,
                      const float* __restrict__ w1, const float* __restrict__ b1,
                      const float* __restrict__ w2, const float* __restrict__ b2,
                      float* __restrict__ out) {
    int t = blockIdx.x * 256 + threadIdx.x;
    if (t >= NG) return;
    const float* gv = g + (size_t)t * REC;
    float gl[REC];
    #pragma unroll
    for (int k = 0; k < REC; ++k) gl[k] = gv[k];
    float acc = b2[0];
    for (int j = 0; j < OHID; ++j) {
        float s = b1[j];
        #pragma unroll
        for (int k = 0; k < REC; ++k) s += gl[k] * w1[k * OHID + j];
        acc += tanhf(s) * w2[j];
    }
    out[t] = acc;
}

extern "C" void kernel_launch(void* const* d_in, const int* in_sizes, int n_in,
                              void* d_out, int out_size, void* d_ws, size_t ws_size,
                              hipStream_t stream) {
    const float* atom    = (const float*)d_in[0];
    const float* bond    = (const float*)d_in[1];
    const int*   parent  = (const int*)d_in[2];
    const int*   child   = (const int*)d_in[3];
    const int*   depth   = (const int*)d_in[4];
    const int*   gid     = (const int*)d_in[5];
    const float* isr     = (const float*)d_in[6];
    const float* inner_w = (const float*)d_in[7];
    const float* inner_b = (const float*)d_in[8];
    const float* net_w1  = (const float*)d_in[9];
    const float* net_b1  = (const float*)d_in[10];
    const float* net_w2  = (const float*)d_in[11];
    const float* net_b2  = (const float*)d_in[12];
    const float* net0_w1 = (const float*)d_in[13];
    const float* net0_b1 = (const float*)d_in[14];
    const float* net0_w2 = (const float*)d_in[15];
    const float* net0_b2 = (const float*)d_in[16];
    const float* out_w1  = (const float*)d_in[17];
    const float* out_b1  = (const float*)d_in[18];
    const float* out_w2  = (const float*)d_in[19];
    const float* out_b2  = (const float*)d_in[20];
    float* out = (float*)d_out;

    char* ws = (char*)d_ws;
    size_t o = 0;
    float*  h_s      = (float*)(ws + o);   o += (size_t)NN * REC * 4;      // 83.9 MB
    float4* adj      = (float4*)(ws + o);  o += (size_t)NE * 16;           // 15.7 MB
    float*  g        = (float*)(ws + o);   o += (size_t)NG * REC * 4;      // 1.3 MB
    int* node_list   = (int*)(ws + o);     o += (size_t)NN * 4;            // 4.2 MB
    int* inv         = (int*)(ws + o);     o += (size_t)NN * 4;            // 4.2 MB
    int* cnt_p       = (int*)(ws + o);     o += (size_t)NN * 4;            // 4.2 MB
    int* row_ptr     = (int*)(ws + o);     o += (size_t)(NN + 4) * 4;      // 4.2 MB
    int* bsum        = (int*)(ws + o);     o += SCAN_B * 4;
    int* boff        = (int*)(ws + o);     o += SCAN_B * 4;
    int* cnt         = (int*)(ws + o);     o += NBIN * 4;
    int* off         = (int*)(ws + o);     o += (NBIN + 1) * 4;
    int* cur         = (int*)(ws + o);     o += NBIN * 4 + 12;
    unsigned char* hc = (unsigned char*)(ws + o); o += (size_t)NN;         // 1.0 MB
    // total ~119 MB

    dim3 B(256);
    int nbN = (NN + 255) / 256;
    int nbE = (NE + 255) / 256;

    k_init<<<nbN, B, 0, stream>>>(hc, cnt);
    k_mark<<<nbE, B, 0, stream>>>(parent, hc);
    k_hist<<<nbN, B, 0, stream>>>(depth, hc, cnt);
    k_scan<<<1, 64, 0, stream>>>(cnt, off, cur);
    k_scatter<<<nbN, B, 0, stream>>>(depth, hc, cur, node_list, inv);
    k_zero_cntp<<<nbN, B, 0, stream>>>(cnt_p);
    k_histp<<<nbE, B, 0, stream>>>(parent, inv, cnt_p);
    k_scanA<<<SCAN_B, SCAN_T, 0, stream>>>(cnt_p, row_ptr, bsum);
    k_scanB<<<1, SCAN_B, 0, stream>>>(bsum, boff, row_ptr);
    k_scanC<<<nbN, B, 0, stream>>>(row_ptr, boff, cnt_p);
    k_adj<<<nbE, B, 0, stream>>>(parent, child, bond, inv, row_ptr, cnt_p, adj);
    k_leaf<<<1024, B, 0, stream>>>(off, node_list, atom,
                                   net0_w1, net0_b1, net0_w2, net0_b2, h_s);
    for (int d = MAXD - 2; d >= 0; --d)
        k_level<<<512, B, 0, stream>>>(d, off, node_list, row_ptr, adj, atom,
                                       net_w1, net_b1, net_w2, net_b2,
                                       inner_w, inner_b, h_s);
    k_zero_g<<<(NG * REC + 255) / 256, B, 0, stream>>>(g);
    k_root<<<nbN, B, 0, stream>>>(isr, gid, inv, h_s, g);
    k_out<<<(NG + 255) / 256, B, 0, stream>>>(g, out_w1, out_b1, out_w2, out_b2, out);
}

// Round 5
// 2684.347 us; speedup vs baseline: 2.2640x; 1.3113x over previous
//
#include <hip/hip_runtime.h>

#define ATOM  14
#define BOND  3
#define INNER 20
#define HID   34
#define REC   20
#define OHID  25
#define NN    1048576
#define NE    983040
#define NG    16384
#define MAXD  16
#define NBIN  32

#define SCAN_B 512     // NN / 2048
#define SCAN_T 256
#define SCAN_E 8       // 2048 per block

__device__ __forceinline__ float leaky(float x) { return x >= 0.f ? x : 0.01f * x; }

// ---------- prep ----------
__global__ void k_init(int* cnt_i, int* pp_c, float* g, int* cnt16) {
    int i = blockIdx.x * 256 + threadIdx.x;
    if (i < NN) { cnt_i[i] = 0; pp_c[i] = -1; }
    if (i < NG * REC) g[i] = 0.f;
    if (i < NBIN) cnt16[i] = 0;
}

// per-node child count (also serves as has-child flag)
__global__ void k_mark(const int* __restrict__ parent, int* __restrict__ cnt_i) {
    int e = blockIdx.x * 256 + threadIdx.x;
    if (e < NE) atomicAdd(&cnt_i[parent[e]], 1);
}

__device__ __forceinline__ int node_bin(int d, bool c) {
    return (c && d < 15) ? d : 16 + d;   // internal by depth; leaf-like 16+depth
}

__global__ void k_hist(const int* __restrict__ depth, const int* __restrict__ cnt_i,
                       int* __restrict__ cnt16) {
    __shared__ int lh[NBIN];
    int t = threadIdx.x;
    if (t < NBIN) lh[t] = 0;
    __syncthreads();
    int i = blockIdx.x * 256 + t;
    if (i < NN) atomicAdd(&lh[node_bin(depth[i], cnt_i[i] > 0)], 1);
    __syncthreads();
    if (t < NBIN && lh[t]) atomicAdd(&cnt16[t], lh[t]);
}

__global__ void k_scan16(const int* __restrict__ cnt16, int* __restrict__ off,
                         int* __restrict__ cur) {
    if (threadIdx.x == 0 && blockIdx.x == 0) {
        int s = 0;
        for (int d = 0; d < NBIN; ++d) { off[d] = s; cur[d] = s; s += cnt16[d]; }
        off[NBIN] = s;
    }
}

// counting-sort nodes into position space; record root-gid per position
__global__ void k_scatter(const int* __restrict__ depth, const int* __restrict__ cnt_i,
                          const float* __restrict__ isr, const int* __restrict__ gid,
                          int* __restrict__ cur, int* __restrict__ node_list,
                          int* __restrict__ inv, int* __restrict__ groot_s) {
    __shared__ int lh[NBIN];
    __shared__ int base[NBIN];
    int t = threadIdx.x;
    if (t < NBIN) lh[t] = 0;
    __syncthreads();
    int i = blockIdx.x * 256 + t;
    int b = 0, r = 0;
    bool live = (i < NN);
    if (live) { b = node_bin(depth[i], cnt_i[i] > 0); r = atomicAdd(&lh[b], 1); }
    __syncthreads();
    if (t < NBIN && lh[t]) base[t] = atomicAdd(&cur[t], lh[t]);
    __syncthreads();
    if (live) {
        int pos = base[b] + r;
        node_list[pos] = i;
        inv[i] = pos;
        groot_s[pos] = (isr[i] != 0.f) ? gid[i] : -1;
    }
}

// per-child: parent position + bond (each node has <=1 parent edge: replace=False)
__global__ void k_eprep(const int* __restrict__ parent, const int* __restrict__ child,
                        const float* __restrict__ bond, const int* __restrict__ inv,
                        int* __restrict__ pp_c, float* __restrict__ bond_s) {
    int e = blockIdx.x * 256 + threadIdx.x;
    if (e >= NE) return;
    int cpos = inv[child[e]];
    int pp   = inv[parent[e]];
    pp_c[cpos] = pp;
    bond_s[(size_t)cpos * BOND + 0] = bond[(size_t)e * BOND + 0];
    bond_s[(size_t)cpos * BOND + 1] = bond[(size_t)e * BOND + 1];
    bond_s[(size_t)cpos * BOND + 2] = bond[(size_t)e * BOND + 2];
}

// exclusive scan of per-position child counts -> row_ptr
__global__ void k_scanA(const int* __restrict__ cnt_i, const int* __restrict__ node_list,
                        int* __restrict__ row_ptr, int* __restrict__ bsum) {
    __shared__ int s[SCAN_T];
    int b = blockIdx.x, t = threadIdx.x;
    int base = b * SCAN_T * SCAN_E + t * SCAN_E;
    int v[SCAN_E];
    int sum = 0;
    #pragma unroll
    for (int k = 0; k < SCAN_E; ++k) { v[k] = cnt_i[node_list[base + k]]; sum += v[k]; }
    s[t] = sum;
    __syncthreads();
    for (int ofs = 1; ofs < SCAN_T; ofs <<= 1) {
        int x = (t >= ofs) ? s[t - ofs] : 0;
        __syncthreads();
        s[t] += x;
        __syncthreads();
    }
    int run = s[t] - sum;
    #pragma unroll
    for (int k = 0; k < SCAN_E; ++k) { row_ptr[base + k] = run; run += v[k]; }
    if (t == SCAN_T - 1) bsum[b] = s[t];
}

__global__ void k_scanB(const int* __restrict__ bsum, int* __restrict__ boff,
                        int* __restrict__ row_ptr) {
    __shared__ int s[SCAN_B];
    int t = threadIdx.x;          // 512 threads
    int v = bsum[t];
    s[t] = v;
    __syncthreads();
    for (int ofs = 1; ofs < SCAN_B; ofs <<= 1) {
        int x = (t >= ofs) ? s[t - ofs] : 0;
        __syncthreads();
        s[t] += x;
        __syncthreads();
    }
    boff[t] = s[t] - v;
    if (t == SCAN_B - 1) row_ptr[NN] = s[t];
}

// finalize row_ptr; zero inv for reuse as rank counters
__global__ void k_scanC(int* __restrict__ row_ptr, const int* __restrict__ boff,
                        int* __restrict__ inv) {
    int i = blockIdx.x * 256 + threadIdx.x;
    if (i < NN) { row_ptr[i] += boff[i >> 11]; inv[i] = 0; }
}

// CSR child lists (positions only)
__global__ void k_adj(const int* __restrict__ pp_c, const int* __restrict__ row_ptr,
                      int* __restrict__ rank_cnt, int* __restrict__ adjc) {
    int pos = blockIdx.x * 256 + threadIdx.x;
    if (pos >= NN) return;
    int pp = pp_c[pos];
    if (pp < 0) return;
    int r = atomicAdd(&rank_cnt[pp], 1);
    adjc[row_ptr[pp] + r] = pos;
}

// ---------- fused producers ----------
__device__ __forceinline__ void emit(int pos, const float* __restrict__ o,
                                     const int* __restrict__ groot_s,
                                     const int* __restrict__ pp_c,
                                     const float* __restrict__ bond_s,
                                     const float* __restrict__ iw,
                                     const float* __restrict__ ib,
                                     float* __restrict__ g, float* __restrict__ msg_s) {
    int gr = groot_s[pos];
    if (gr >= 0) {
        float* gp = g + (size_t)gr * REC;
        #pragma unroll
        for (int j = 0; j < REC; ++j) atomicAdd(&gp[j], o[j]);
    }
    if (pp_c[pos] >= 0) {
        float b0 = bond_s[(size_t)pos * BOND + 0];
        float b1 = bond_s[(size_t)pos * BOND + 1];
        float b2 = bond_s[(size_t)pos * BOND + 2];
        float m[INNER];
        #pragma unroll
        for (int j = 0; j < INNER; ++j)
            m[j] = ib[j] + b0 * iw[0 * INNER + j] + b1 * iw[1 * INNER + j]
                         + b2 * iw[2 * INNER + j];
        #pragma unroll
        for (int k = 0; k < REC; ++k) {
            float ok = o[k];
            #pragma unroll
            for (int j = 0; j < INNER; ++j) m[j] += ok * iw[(BOND + k) * INNER + j];
        }
        float4* mp = (float4*)(msg_s + (size_t)pos * REC);
        #pragma unroll
        for (int j = 0; j < 5; ++j)
            mp[j] = make_float4(leaky(m[4*j]), leaky(m[4*j+1]),
                                leaky(m[4*j+2]), leaky(m[4*j+3]));
    }
}

// leaf-like nodes: positions [off[16], NN)
__global__ void k_leaf(const int* __restrict__ off, const int* __restrict__ node_list,
                       const int* __restrict__ groot_s, const int* __restrict__ pp_c,
                       const float* __restrict__ bond_s, const float* __restrict__ atom,
                       const float* __restrict__ w1, const float* __restrict__ b1,
                       const float* __restrict__ w2, const float* __restrict__ b2,
                       const float* __restrict__ iw, const float* __restrict__ ib,
                       float* __restrict__ g, float* __restrict__ msg_s) {
    int p0 = off[16];
    for (int pos = p0 + blockIdx.x * blockDim.x + threadIdx.x; pos < NN;
         pos += gridDim.x * blockDim.x) {
        int i = node_list[pos];
        const float2* a2 = (const float2*)(atom + (size_t)i * ATOM);
        float a[ATOM];
        #pragma unroll
        for (int k = 0; k < 7; ++k) { float2 v = a2[k]; a[2*k] = v.x; a[2*k+1] = v.y; }
        float hid[HID];
        #pragma unroll
        for (int j = 0; j < HID; ++j) hid[j] = b1[j];
        for (int k = 0; k < ATOM; ++k) {
            float ak = a[k];
            #pragma unroll
            for (int j = 0; j < HID; ++j) hid[j] += ak * w1[k * HID + j];
        }
        #pragma unroll
        for (int j = 0; j < HID; ++j) hid[j] = leaky(hid[j]);
        float o[REC];
        #pragma unroll
        for (int j = 0; j < REC; ++j) o[j] = b2[j];
        for (int k = 0; k < HID; ++k) {
            float hk = hid[k];
            #pragma unroll
            for (int j = 0; j < REC; ++j) o[j] += hk * w2[k * REC + j];
        }
        #pragma unroll
        for (int j = 0; j < REC; ++j) o[j] = leaky(o[j]);
        emit(pos, o, groot_s, pp_c, bond_s, iw, ib, g, msg_s);
    }
}

// internal nodes at depth d: gather children's msgs (L2-hot), MLP, emit
__global__ void k_level(int d, const int* __restrict__ off, const int* __restrict__ node_list,
                        const int* __restrict__ row_ptr, const int* __restrict__ adjc,
                        const int* __restrict__ groot_s, const int* __restrict__ pp_c,
                        const float* __restrict__ bond_s, const float* __restrict__ atom,
                        const float* __restrict__ w1, const float* __restrict__ b1,
                        const float* __restrict__ w2, const float* __restrict__ b2,
                        const float* __restrict__ iw, const float* __restrict__ ib,
                        float* __restrict__ g, float* __restrict__ msg_s) {
    int p0 = off[d], p1 = off[d + 1];
    for (int pos = p0 + blockIdx.x * blockDim.x + threadIdx.x; pos < p1;
         pos += gridDim.x * blockDim.x) {
        int i = node_list[pos];                  // independent chain: issue early
        int r0 = row_ptr[pos], r1 = row_ptr[pos + 1];
        float isum[INNER];
        #pragma unroll
        for (int j = 0; j < INNER; ++j) isum[j] = 0.f;
        for (int r = r0; r < r1; ++r) {
            int cpos = adjc[r];
            const float4* mp = (const float4*)(msg_s + (size_t)cpos * REC);
            #pragma unroll
            for (int q = 0; q < 5; ++q) {
                float4 v = mp[q];
                isum[4*q]   += v.x; isum[4*q+1] += v.y;
                isum[4*q+2] += v.z; isum[4*q+3] += v.w;
            }
        }
        const float2* a2 = (const float2*)(atom + (size_t)i * ATOM);
        float a[ATOM];
        #pragma unroll
        for (int k = 0; k < 7; ++k) { float2 v = a2[k]; a[2*k] = v.x; a[2*k+1] = v.y; }
        float hid[HID];
        #pragma unroll
        for (int j = 0; j < HID; ++j) hid[j] = b1[j];
        for (int k = 0; k < ATOM; ++k) {
            float xk = a[k];
            #pragma unroll
            for (int j = 0; j < HID; ++j) hid[j] += xk * w1[k * HID + j];
        }
        for (int k = 0; k < INNER; ++k) {
            float xk = isum[k];
            #pragma unroll
            for (int j = 0; j < HID; ++j) hid[j] += xk * w1[(ATOM + k) * HID + j];
        }
        #pragma unroll
        for (int j = 0; j < HID; ++j) hid[j] = leaky(hid[j]);
        float o[REC];
        #pragma unroll
        for (int j = 0; j < REC; ++j) o[j] = b2[j];
        for (int k = 0; k < HID; ++k) {
            float hk = hid[k];
            #pragma unroll
            for (int j = 0; j < REC; ++j) o[j] += hk * w2[k * REC + j];
        }
        #pragma unroll
        for (int j = 0; j < REC; ++j) o[j] = leaky(o[j]);
        emit(pos, o, groot_s, pp_c, bond_s, iw, ib, g, msg_s);
    }
}

// ---------- readout ----------
__global__ void k_out(const float* __restrict__ g,
                      const float* __restrict__ w1, const float* __restrict__ b1,
                      const float* __restrict__ w2, const float* __restrict__ b2,
                      float* __restrict__ out) {
    int t = blockIdx.x * 256 + threadIdx.x;
    if (t >= NG) return;
    const float* gv = g + (size_t)t * REC;
    float gl[REC];
    #pragma unroll
    for (int k = 0; k < REC; ++k) gl[k] = gv[k];
    float acc = b2[0];
    for (int j = 0; j < OHID; ++j) {
        float s = b1[j];
        #pragma unroll
        for (int k = 0; k < REC; ++k) s += gl[k] * w1[k * OHID + j];
        acc += tanhf(s) * w2[j];
    }
    out[t] = acc;
}

extern "C" void kernel_launch(void* const* d_in, const int* in_sizes, int n_in,
                              void* d_out, int out_size, void* d_ws, size_t ws_size,
                              hipStream_t stream) {
    const float* atom    = (const float*)d_in[0];
    const float* bond    = (const float*)d_in[1];
    const int*   parent  = (const int*)d_in[2];
    const int*   child   = (const int*)d_in[3];
    const int*   depth   = (const int*)d_in[4];
    const int*   gid     = (const int*)d_in[5];
    const float* isr     = (const float*)d_in[6];
    const float* inner_w = (const float*)d_in[7];
    const float* inner_b = (const float*)d_in[8];
    const float* net_w1  = (const float*)d_in[9];
    const float* net_b1  = (const float*)d_in[10];
    const float* net_w2  = (const float*)d_in[11];
    const float* net_b2  = (const float*)d_in[12];
    const float* net0_w1 = (const float*)d_in[13];
    const float* net0_b1 = (const float*)d_in[14];
    const float* net0_w2 = (const float*)d_in[15];
    const float* net0_b2 = (const float*)d_in[16];
    const float* out_w1  = (const float*)d_in[17];
    const float* out_b1  = (const float*)d_in[18];
    const float* out_w2  = (const float*)d_in[19];
    const float* out_b2  = (const float*)d_in[20];
    float* out = (float*)d_out;

    char* ws = (char*)d_ws;
    size_t o = 0;
    float* msg_s    = (float*)(ws + o);  o += (size_t)NN * REC * 4;    // 83.9 MB
    float* g        = (float*)(ws + o);  o += (size_t)NG * REC * 4;    // 1.3 MB
    float* bond_s   = (float*)(ws + o);  o += (size_t)NN * BOND * 4;   // 12.6 MB
    int* node_list  = (int*)(ws + o);    o += (size_t)NN * 4;          // 4.2 MB
    int* inv        = (int*)(ws + o);    o += (size_t)NN * 4;          // 4.2 MB (reused as adj rank cnt)
    int* pp_c       = (int*)(ws + o);    o += (size_t)NN * 4;          // 4.2 MB
    int* groot_s    = (int*)(ws + o);    o += (size_t)NN * 4;          // 4.2 MB
    int* row_ptr    = (int*)(ws + o);    o += (size_t)(NN + 4) * 4;    // 4.2 MB
    int* cnt_i      = (int*)(ws + o);    o += (size_t)NN * 4;          // 4.2 MB
    int* adjc       = (int*)(ws + o);    o += (size_t)NE * 4;          // 3.9 MB
    int* bsum       = (int*)(ws + o);    o += SCAN_B * 4;
    int* boff       = (int*)(ws + o);    o += SCAN_B * 4;
    int* cnt16      = (int*)(ws + o);    o += NBIN * 4;
    int* off        = (int*)(ws + o);    o += (NBIN + 1) * 4;
    int* cur        = (int*)(ws + o);    o += NBIN * 4 + 12;
    // total ~127 MB

    dim3 B(256);
    int nbN = (NN + 255) / 256;
    int nbE = (NE + 255) / 256;

    k_init<<<nbN, B, 0, stream>>>(cnt_i, pp_c, g, cnt16);
    k_mark<<<nbE, B, 0, stream>>>(parent, cnt_i);
    k_hist<<<nbN, B, 0, stream>>>(depth, cnt_i, cnt16);
    k_scan16<<<1, 64, 0, stream>>>(cnt16, off, cur);
    k_scatter<<<nbN, B, 0, stream>>>(depth, cnt_i, isr, gid, cur, node_list, inv, groot_s);
    k_eprep<<<nbE, B, 0, stream>>>(parent, child, bond, inv, pp_c, bond_s);
    k_scanA<<<SCAN_B, SCAN_T, 0, stream>>>(cnt_i, node_list, row_ptr, bsum);
    k_scanB<<<1, SCAN_B, 0, stream>>>(bsum, boff, row_ptr);
    k_scanC<<<nbN, B, 0, stream>>>(row_ptr, boff, inv);
    k_adj<<<nbN, B, 0, stream>>>(pp_c, row_ptr, inv, adjc);
    k_leaf<<<1024, B, 0, stream>>>(off, node_list, groot_s, pp_c, bond_s, atom,
                                   net0_w1, net0_b1, net0_w2, net0_b2,
                                   inner_w, inner_b, g, msg_s);
    for (int d = MAXD - 2; d >= 0; --d)
        k_level<<<320, B, 0, stream>>>(d, off, node_list, row_ptr, adjc, groot_s, pp_c,
                                       bond_s, atom, net_w1, net_b1, net_w2, net_b2,
                                       inner_w, inner_b, g, msg_s);
    k_out<<<(NG + 255) / 256, B, 0, stream>>>(g, out_w1, out_b1, out_w2, out_b2, out);
}

// Round 6
// 2216.098 us; speedup vs baseline: 2.7424x; 1.2113x over previous
//
#include <hip/hip_runtime.h>

#define ATOM  14
#define BOND  3
#define INNER 20
#define HID   34
#define REC   20
#define OHID  25
#define NN    1048576
#define NE    983040
#define NG    16384
#define NBIN  32

#define NB    512
#define NT    256
#define GT    (NB*NT)
#define CHUNK 2048          // NN / NB
#define SE    8             // CHUNK / NT

__device__ __forceinline__ float leaky(float x) { return x >= 0.f ? x : 0.01f * x; }

__device__ __forceinline__ int node_bin(int d, bool c) {
    return (c && d < 15) ? d : 16 + d;   // internal by depth; leaf-like 16+depth
}

// grid-wide barrier: device-scope counter + agent fences (cross-XCD safe)
__device__ __forceinline__ void gbar(int* bar, int goal) {
    __syncthreads();
    if (threadIdx.x == 0) {
        __threadfence();   // release: write back dirty L2 (per-XCD)
        __hip_atomic_fetch_add(bar, 1, __ATOMIC_RELEASE, __HIP_MEMORY_SCOPE_AGENT);
        while (__hip_atomic_load(bar, __ATOMIC_RELAXED, __HIP_MEMORY_SCOPE_AGENT) < goal)
            __builtin_amdgcn_s_sleep(2);
        __threadfence();   // acquire: invalidate L1/L2
    }
    __syncthreads();
}

__device__ __forceinline__ void emit(int pos, const float* __restrict__ o,
                                     const int* __restrict__ groot_s,
                                     const int* __restrict__ pp_c,
                                     const float* __restrict__ bond_s,
                                     const float* __restrict__ iw,
                                     const float* __restrict__ ib,
                                     float* __restrict__ g, float* __restrict__ msg_s) {
    int gr = groot_s[pos];
    if (gr >= 0) {
        float* gp = g + (size_t)gr * REC;
        #pragma unroll
        for (int j = 0; j < REC; ++j) atomicAdd(&gp[j], o[j]);
    }
    if (pp_c[pos] >= 0) {
        float b0 = bond_s[(size_t)pos * BOND + 0];
        float b1 = bond_s[(size_t)pos * BOND + 1];
        float b2 = bond_s[(size_t)pos * BOND + 2];
        float m[INNER];
        #pragma unroll
        for (int j = 0; j < INNER; ++j)
            m[j] = ib[j] + b0 * iw[0 * INNER + j] + b1 * iw[1 * INNER + j]
                         + b2 * iw[2 * INNER + j];
        #pragma unroll
        for (int k = 0; k < REC; ++k) {
            float ok = o[k];
            #pragma unroll
            for (int j = 0; j < INNER; ++j) m[j] += ok * iw[(BOND + k) * INNER + j];
        }
        float4* mp = (float4*)(msg_s + (size_t)pos * REC);
        #pragma unroll
        for (int j = 0; j < 5; ++j)
            mp[j] = make_float4(leaky(m[4*j]), leaky(m[4*j+1]),
                                leaky(m[4*j+2]), leaky(m[4*j+3]));
    }
}

__global__ void k_zero_bar(int* bar) {
    if (threadIdx.x == 0 && blockIdx.x == 0) *bar = 0;
}

__global__ __launch_bounds__(NT) void k_fused(
    const float* __restrict__ atom, const float* __restrict__ bond,
    const int* __restrict__ parent, const int* __restrict__ child,
    const int* __restrict__ depth, const int* __restrict__ gid,
    const float* __restrict__ isr,
    const float* __restrict__ iw, const float* __restrict__ ib,
    const float* __restrict__ nw1, const float* __restrict__ nb1,
    const float* __restrict__ nw2, const float* __restrict__ nb2,
    const float* __restrict__ l0w1, const float* __restrict__ l0b1,
    const float* __restrict__ l0w2, const float* __restrict__ l0b2,
    const float* __restrict__ ow1, const float* __restrict__ ob1,
    const float* __restrict__ ow2, const float* __restrict__ ob2,
    float* __restrict__ out,
    float* msg_s, float* g, float* bond_s,
    int* node_list, int* inv, int* pp_c, int* groot_s,
    int* row_ptr, int* cnt_i, int* adjc, int* bsum, int* boff,
    int* cnt16, int* off, int* cur, int* bar)
{
    __shared__ int sh[512];
    const int t = threadIdx.x;
    const int tid = blockIdx.x * NT + t;
    int ep = 0;
    const volatile int* voff = off;

    // ---- P0: init ----
    for (int i = tid; i < NN; i += GT) { cnt_i[i] = 0; pp_c[i] = -1; }
    for (int i = tid; i < NG * REC; i += GT) g[i] = 0.f;
    if (tid < NBIN) cnt16[tid] = 0;
    gbar(bar, NB * ++ep);

    // ---- P1: child counts ----
    for (int e = tid; e < NE; e += GT) atomicAdd(&cnt_i[parent[e]], 1);
    gbar(bar, NB * ++ep);

    // ---- P2: 32-bin histogram ----
    if (t < NBIN) sh[t] = 0;
    __syncthreads();
    for (int i = tid; i < NN; i += GT) atomicAdd(&sh[node_bin(depth[i], cnt_i[i] > 0)], 1);
    __syncthreads();
    if (t < NBIN && sh[t]) atomicAdd(&cnt16[t], sh[t]);
    gbar(bar, NB * ++ep);

    // ---- P3: bin scan (single thread) ----
    if (tid == 0) {
        int s = 0;
        for (int d = 0; d < NBIN; ++d) { off[d] = s; cur[d] = s; s += cnt16[d]; }
        off[NBIN] = s;
    }
    gbar(bar, NB * ++ep);

    // ---- P4: counting sort into position space ----
    {
        int* lh = sh; int* bs = sh + NBIN;
        for (int chunk = blockIdx.x; chunk < NN / NT; chunk += NB) {
            __syncthreads();
            if (t < NBIN) lh[t] = 0;
            __syncthreads();
            int i = chunk * NT + t;
            int b = node_bin(depth[i], cnt_i[i] > 0);
            int r = atomicAdd(&lh[b], 1);
            __syncthreads();
            if (t < NBIN && lh[t]) bs[t] = atomicAdd(&cur[t], lh[t]);
            __syncthreads();
            int pos = bs[b] + r;
            node_list[pos] = i;
            inv[i] = pos;
            groot_s[pos] = (isr[i] != 0.f) ? gid[i] : -1;
        }
    }
    gbar(bar, NB * ++ep);

    // ---- P5: edge prep + per-chunk scan of child counts ----
    for (int e = tid; e < NE; e += GT) {
        int cpos = inv[child[e]];
        pp_c[cpos] = inv[parent[e]];
        bond_s[(size_t)cpos * BOND + 0] = bond[(size_t)e * BOND + 0];
        bond_s[(size_t)cpos * BOND + 1] = bond[(size_t)e * BOND + 1];
        bond_s[(size_t)cpos * BOND + 2] = bond[(size_t)e * BOND + 2];
    }
    {
        int base0 = blockIdx.x * CHUNK + t * SE;
        int v[SE]; int sum = 0;
        #pragma unroll
        for (int k = 0; k < SE; ++k) { v[k] = cnt_i[node_list[base0 + k]]; sum += v[k]; }
        __syncthreads();
        sh[t] = sum;
        __syncthreads();
        for (int ofs = 1; ofs < NT; ofs <<= 1) {
            int x = (t >= ofs) ? sh[t - ofs] : 0;
            __syncthreads();
            sh[t] += x;
            __syncthreads();
        }
        int run = sh[t] - sum;
        #pragma unroll
        for (int k = 0; k < SE; ++k) { row_ptr[base0 + k] = run; run += v[k]; }
        if (t == NT - 1) bsum[blockIdx.x] = sh[t];
    }
    gbar(bar, NB * ++ep);

    // ---- P6: scan block sums (block 0) ----
    if (blockIdx.x == 0) {
        int v0 = bsum[2 * t], v1 = bsum[2 * t + 1];
        int p = v0 + v1;
        sh[t] = p;
        __syncthreads();
        for (int ofs = 1; ofs < NT; ofs <<= 1) {
            int x = (t >= ofs) ? sh[t - ofs] : 0;
            __syncthreads();
            sh[t] += x;
            __syncthreads();
        }
        int excl = sh[t] - p;
        boff[2 * t] = excl;
        boff[2 * t + 1] = excl + v0;
        if (t == NT - 1) row_ptr[NN] = sh[t];
    }
    gbar(bar, NB * ++ep);

    // ---- P7: finalize row_ptr; zero rank counters (reuse inv) ----
    for (int i = tid; i < NN; i += GT) { row_ptr[i] += boff[i >> 11]; inv[i] = 0; }
    gbar(bar, NB * ++ep);

    // ---- P8: CSR child lists ----
    for (int pos = tid; pos < NN; pos += GT) {
        int pp = pp_c[pos];
        if (pp >= 0) {
            int r = atomicAdd(&inv[pp], 1);
            adjc[row_ptr[pp] + r] = pos;
        }
    }
    gbar(bar, NB * ++ep);

    // ---- P9: leaf MLP + emit ----
    {
        int p0 = voff[16];
        for (int pos = p0 + tid; pos < NN; pos += GT) {
            int i = node_list[pos];
            const float2* a2 = (const float2*)(atom + (size_t)i * ATOM);
            float a[ATOM];
            #pragma unroll
            for (int k = 0; k < 7; ++k) { float2 v = a2[k]; a[2*k] = v.x; a[2*k+1] = v.y; }
            float hid[HID];
            #pragma unroll
            for (int j = 0; j < HID; ++j) hid[j] = l0b1[j];
            for (int k = 0; k < ATOM; ++k) {
                float ak = a[k];
                #pragma unroll
                for (int j = 0; j < HID; ++j) hid[j] += ak * l0w1[k * HID + j];
            }
            #pragma unroll
            for (int j = 0; j < HID; ++j) hid[j] = leaky(hid[j]);
            float o[REC];
            #pragma unroll
            for (int j = 0; j < REC; ++j) o[j] = l0b2[j];
            for (int k = 0; k < HID; ++k) {
                float hk = hid[k];
                #pragma unroll
                for (int j = 0; j < REC; ++j) o[j] += hk * l0w2[k * REC + j];
            }
            #pragma unroll
            for (int j = 0; j < REC; ++j) o[j] = leaky(o[j]);
            emit(pos, o, groot_s, pp_c, bond_s, iw, ib, g, msg_s);
        }
    }
    gbar(bar, NB * ++ep);

    // ---- P10..P24: levels d = 14..0 ----
    for (int d = 14; d >= 0; --d) {
        int q0 = voff[d], q1 = voff[d + 1];
        for (int pos = q0 + tid; pos < q1; pos += GT) {
            int i = node_list[pos];
            int r0 = row_ptr[pos], r1 = row_ptr[pos + 1];
            float isum[INNER];
            #pragma unroll
            for (int j = 0; j < INNER; ++j) isum[j] = 0.f;
            for (int r = r0; r < r1; ++r) {
                int cpos = adjc[r];
                const float4* mp = (const float4*)(msg_s + (size_t)cpos * REC);
                #pragma unroll
                for (int q = 0; q < 5; ++q) {
                    float4 v = mp[q];
                    isum[4*q]   += v.x; isum[4*q+1] += v.y;
                    isum[4*q+2] += v.z; isum[4*q+3] += v.w;
                }
            }
            const float2* a2 = (const float2*)(atom + (size_t)i * ATOM);
            float a[ATOM];
            #pragma unroll
            for (int k = 0; k < 7; ++k) { float2 v = a2[k]; a[2*k] = v.x; a[2*k+1] = v.y; }
            float hid[HID];
            #pragma unroll
            for (int j = 0; j < HID; ++j) hid[j] = nb1[j];
            for (int k = 0; k < ATOM; ++k) {
                float xk = a[k];
                #pragma unroll
                for (int j = 0; j < HID; ++j) hid[j] += xk * nw1[k * HID + j];
            }
            for (int k = 0; k < INNER; ++k) {
                float xk = isum[k];
                #pragma unroll
                for (int j = 0; j < HID; ++j) hid[j] += xk * nw1[(ATOM + k) * HID + j];
            }
            #pragma unroll
            for (int j = 0; j < HID; ++j) hid[j] = leaky(hid[j]);
            float o[REC];
            #pragma unroll
            for (int j = 0; j < REC; ++j) o[j] = nb2[j];
            for (int k = 0; k < HID; ++k) {
                float hk = hid[k];
                #pragma unroll
                for (int j = 0; j < REC; ++j) o[j] += hk * nw2[k * REC + j];
            }
            #pragma unroll
            for (int j = 0; j < REC; ++j) o[j] = leaky(o[j]);
            emit(pos, o, groot_s, pp_c, bond_s, iw, ib, g, msg_s);
        }
        gbar(bar, NB * ++ep);
    }

    // ---- P25: graph readout ----
    for (int tg = tid; tg < NG; tg += GT) {
        const float* gv = g + (size_t)tg * REC;
        float gl[REC];
        #pragma unroll
        for (int k = 0; k < REC; ++k) gl[k] = gv[k];
        float acc = ob2[0];
        for (int j = 0; j < OHID; ++j) {
            float s = ob1[j];
            #pragma unroll
            for (int k = 0; k < REC; ++k) s += gl[k] * ow1[k * OHID + j];
            acc += tanhf(s) * ow2[j];
        }
        out[tg] = acc;
    }
}

extern "C" void kernel_launch(void* const* d_in, const int* in_sizes, int n_in,
                              void* d_out, int out_size, void* d_ws, size_t ws_size,
                              hipStream_t stream) {
    const float* atom    = (const float*)d_in[0];
    const float* bond    = (const float*)d_in[1];
    const int*   parent  = (const int*)d_in[2];
    const int*   child   = (const int*)d_in[3];
    const int*   depth   = (const int*)d_in[4];
    const int*   gid     = (const int*)d_in[5];
    const float* isr     = (const float*)d_in[6];
    const float* inner_w = (const float*)d_in[7];
    const float* inner_b = (const float*)d_in[8];
    const float* net_w1  = (const float*)d_in[9];
    const float* net_b1  = (const float*)d_in[10];
    const float* net_w2  = (const float*)d_in[11];
    const float* net_b2  = (const float*)d_in[12];
    const float* net0_w1 = (const float*)d_in[13];
    const float* net0_b1 = (const float*)d_in[14];
    const float* net0_w2 = (const float*)d_in[15];
    const float* net0_b2 = (const float*)d_in[16];
    const float* out_w1  = (const float*)d_in[17];
    const float* out_b1  = (const float*)d_in[18];
    const float* out_w2  = (const float*)d_in[19];
    const float* out_b2  = (const float*)d_in[20];
    float* out = (float*)d_out;

    char* ws = (char*)d_ws;
    size_t o = 0;
    float* msg_s    = (float*)(ws + o);  o += (size_t)NN * REC * 4;    // 83.9 MB
    float* g        = (float*)(ws + o);  o += (size_t)NG * REC * 4;    // 1.3 MB
    float* bond_s   = (float*)(ws + o);  o += (size_t)NN * BOND * 4;   // 12.6 MB
    int* node_list  = (int*)(ws + o);    o += (size_t)NN * 4;          // 4.2 MB
    int* inv        = (int*)(ws + o);    o += (size_t)NN * 4;          // 4.2 MB
    int* pp_c       = (int*)(ws + o);    o += (size_t)NN * 4;          // 4.2 MB
    int* groot_s    = (int*)(ws + o);    o += (size_t)NN * 4;          // 4.2 MB
    int* row_ptr    = (int*)(ws + o);    o += (size_t)(NN + 4) * 4;    // 4.2 MB
    int* cnt_i      = (int*)(ws + o);    o += (size_t)NN * 4;          // 4.2 MB
    int* adjc       = (int*)(ws + o);    o += (size_t)NE * 4;          // 3.9 MB
    int* bsum       = (int*)(ws + o);    o += NB * 4;
    int* boff       = (int*)(ws + o);    o += NB * 4;
    int* cnt16      = (int*)(ws + o);    o += NBIN * 4;
    int* off        = (int*)(ws + o);    o += (NBIN + 1) * 4;
    int* cur        = (int*)(ws + o);    o += NBIN * 4 + 12;
    int* bar        = (int*)(ws + o);    o += 256;                     // own line
    // total ~127 MB

    k_zero_bar<<<1, 64, 0, stream>>>(bar);
    k_fused<<<NB, NT, 0, stream>>>(atom, bond, parent, child, depth, gid, isr,
                                   inner_w, inner_b, net_w1, net_b1, net_w2, net_b2,
                                   net0_w1, net0_b1, net0_w2, net0_b2,
                                   out_w1, out_b1, out_w2, out_b2, out,
                                   msg_s, g, bond_s, node_list, inv, pp_c, groot_s,
                                   row_ptr, cnt_i, adjc, bsum, boff,
                                   cnt16, off, cur, bar);
}